// Round 8
// baseline (127.957 us; speedup 1.0000x reference)
//
#include <hip/hip_runtime.h>
#include <hip/hip_bf16.h>
#include <math.h>

#define B 128
#define C 2048
#define N 196        // H*W
#define K 112
#define KB 113       // K + background
#define MROWS 128    // padded MFMA rows: 0..111 concepts, 112 bg, 113 w_cfc, 114..127 zero
#define XWROW 113
#define NCLS 200
#define CKC (C * K)
#define BKP 72       // X-tile k-stride in u16 (row = 144B; b128 r/w uniform over bank quads)
#define XADV (64 * N)

#define OUT1_OFF 2834944
#define OUT2_OFF 2849280

typedef __attribute__((ext_vector_type(8))) short bf16x8;
typedef __attribute__((ext_vector_type(4))) float f32x4;

__device__ inline unsigned cvtpk(float a, float b) {
    union { __hip_bfloat162 h; unsigned u; } c;
    c.h.x = __float2bfloat16(a);
    c.h.y = __float2bfloat16(b);
    return c.u;
}
__device__ inline const float* row_src(int row, const float* concepts,
                                       const float* background, const float* wcfc) {
    if (row < K) return concepts + (size_t)row * C;
    if (row == K) return background;
    if (row == XWROW) return wcfc;
    return nullptr;
}

// ---------------------------------------------------------------------------
// asq_kernel
// ---------------------------------------------------------------------------
__global__ __launch_bounds__(256)
void asq_kernel(const float* __restrict__ concepts, const float* __restrict__ background,
                const float* __restrict__ wcfc, float* __restrict__ asq) {
    const int row = blockIdx.x;
    const int tid = threadIdx.x;
    const float* src = row_src(row, concepts, background, wcfc);
    float local = 0.f;
    if (src) for (int i = tid; i < C; i += 256) { float v = src[i]; local += v * v; }
    for (int off = 32; off; off >>= 1) local += __shfl_down(local, off);
    __shared__ float red[4];
    if ((tid & 63) == 0) red[tid >> 6] = local;
    __syncthreads();
    if (tid == 0) asq[row] = red[0] + red[1] + red[2] + red[3];
}

// ---------------------------------------------------------------------------
// pack_kernel: A_frag[t][kw][lane][8] bf16 ; lane l holds A[16t+(l&15)][32kw+8*(l>>4)+j]
// ---------------------------------------------------------------------------
__global__ __launch_bounds__(64)
void pack_kernel(const float* __restrict__ concepts, const float* __restrict__ background,
                 const float* __restrict__ wcfc, unsigned short* __restrict__ Afrag) {
    const int t = blockIdx.x;      // 0..7 row tile
    const int kw = blockIdx.y;     // 0..63 k window
    const int l = threadIdx.x;
    const int row = 16 * t + (l & 15);
    const int kb = 32 * kw + 8 * (l >> 4);
    const float* src = row_src(row, concepts, background, wcfc);
    unsigned o[4] = {0u, 0u, 0u, 0u};
    if (src) {
        const float4 f0 = *reinterpret_cast<const float4*>(src + kb);
        const float4 f1 = *reinterpret_cast<const float4*>(src + kb + 4);
        o[0] = cvtpk(f0.x, f0.y); o[1] = cvtpk(f0.z, f0.w);
        o[2] = cvtpk(f1.x, f1.y); o[3] = cvtpk(f1.z, f1.w);
    }
    *reinterpret_cast<uint4*>(Afrag + (((size_t)t * 64 + kw) * 64 + l) * 8) =
        make_uint4(o[0], o[1], o[2], o[3]);
}

// ---------------------------------------------------------------------------
// main_kernel: per (b, ntile64): dots[128][64] = A(128x2048) @ x_b(2048x64) via MFMA
//   4-deep x register ring, 2-deep A ring, fully peeled (no branches in steady
//   loop), double-buffered XT, one raw s_barrier/iter, fused softmax epilogue.
// ---------------------------------------------------------------------------
__global__ __launch_bounds__(256, 2)
void main_kernel(const float* __restrict__ x,
                 const unsigned short* __restrict__ Afrag,
                 const float* __restrict__ asq_g,
                 float* __restrict__ out0,
                 float* __restrict__ lpart) {
    __shared__ __align__(16) char smem[38400];
    unsigned short* XT0 = (unsigned short*)smem;           // [64][72] bf16, buffer 0
    unsigned short* XT1 = (unsigned short*)(smem + 9216);  // buffer 1
    float* dotsL = (float*)smem;                           // epilogue overlay [128][66]
    float* xsqp  = (float*)(smem + 33792);                 // [8][64]
    float* asq_s = (float*)(smem + 35840);                 // [128]
    float* pm    = (float*)(smem + 36352);                 // [4][64]
    float* ps    = (float*)(smem + 37376);                 // [4][64]

    const int tid = threadIdx.x;
    const int lane = tid & 63;
    const int w = tid >> 6;
    const int nt4 = blockIdx.x;
    const int b = blockIdx.y;
    const int n0 = nt4 * 64;

    // staging role: thread covers k-chunk (tid>>5) of 8, n-pair (tid&31)
    const int kc = tid >> 5;
    const int pr = tid & 31;
    const int ns = n0 + 2 * pr;
    const bool v0 = ns < N, v1 = (ns + 1) < N;
    const unsigned mA = v0 ? 0xFFFFFFFFu : 0u;
    const unsigned mB = v1 ? 0xFFFFFFFFu : 0u;
    const int nsc = (ns < N - 2) ? ns : (N - 2);   // clamped, always-valid col pair
    const float* xstage = x + (size_t)b * C * N + nsc + (size_t)kc * 8 * N;

    f32x4 acc[2][4];
#pragma unroll
    for (int i = 0; i < 2; ++i)
#pragma unroll
        for (int j = 0; j < 4; ++j) acc[i][j] = (f32x4){0.f, 0.f, 0.f, 0.f};
    float xs0 = 0.f, xs1 = 0.f;

// pure unconditional loads from running pointer; advances one K-step
#define STAGE_LOAD(R) do {                                                      \
        (R##0) = *reinterpret_cast<const float2*>(xstage + (size_t)0 * N);      \
        (R##1) = *reinterpret_cast<const float2*>(xstage + (size_t)1 * N);      \
        (R##2) = *reinterpret_cast<const float2*>(xstage + (size_t)2 * N);      \
        (R##3) = *reinterpret_cast<const float2*>(xstage + (size_t)3 * N);      \
        (R##4) = *reinterpret_cast<const float2*>(xstage + (size_t)4 * N);      \
        (R##5) = *reinterpret_cast<const float2*>(xstage + (size_t)5 * N);      \
        (R##6) = *reinterpret_cast<const float2*>(xstage + (size_t)6 * N);      \
        (R##7) = *reinterpret_cast<const float2*>(xstage + (size_t)7 * N);      \
        xstage += XADV;                                                         \
    } while (0)

#define LOAD_A(A, it) do {                                                      \
        _Pragma("unroll")                                                       \
        for (int rt_ = 0; rt_ < 2; ++rt_)                                       \
            _Pragma("unroll")                                                   \
            for (int kw_ = 0; kw_ < 2; ++kw_)                                   \
                A[rt_ * 2 + kw_] = *reinterpret_cast<const bf16x8*>(            \
                    Afrag + ((((size_t)(2 * w + rt_)) * 64 + (it) * 2 + kw_)    \
                             * 64 + lane) * 8);                                 \
    } while (0)

#define PACK_WRITE(R, XTB) do {                                                 \
        unsigned w0_[4], w1_[4];                                                \
        xs0 += (R##0).x * (R##0).x + (R##1).x * (R##1).x;                       \
        xs1 += (R##0).y * (R##0).y + (R##1).y * (R##1).y;                       \
        w0_[0] = cvtpk((R##0).x, (R##1).x) & mA;                                \
        w1_[0] = cvtpk((R##0).y, (R##1).y) & mB;                                \
        xs0 += (R##2).x * (R##2).x + (R##3).x * (R##3).x;                       \
        xs1 += (R##2).y * (R##2).y + (R##3).y * (R##3).y;                       \
        w0_[1] = cvtpk((R##2).x, (R##3).x) & mA;                                \
        w1_[1] = cvtpk((R##2).y, (R##3).y) & mB;                                \
        xs0 += (R##4).x * (R##4).x + (R##5).x * (R##5).x;                       \
        xs1 += (R##4).y * (R##4).y + (R##5).y * (R##5).y;                       \
        w0_[2] = cvtpk((R##4).x, (R##5).x) & mA;                                \
        w1_[2] = cvtpk((R##4).y, (R##5).y) & mB;                                \
        xs0 += (R##6).x * (R##6).x + (R##7).x * (R##7).x;                       \
        xs1 += (R##6).y * (R##6).y + (R##7).y * (R##7).y;                       \
        w0_[3] = cvtpk((R##6).x, (R##7).x) & mA;                                \
        w1_[3] = cvtpk((R##6).y, (R##7).y) & mB;                                \
        *reinterpret_cast<uint4*>(XTB + (size_t)(2 * pr) * BKP + kc * 8) =      \
            make_uint4(w0_[0], w0_[1], w0_[2], w0_[3]);                         \
        *reinterpret_cast<uint4*>(XTB + (size_t)(2 * pr + 1) * BKP + kc * 8) =  \
            make_uint4(w1_[0], w1_[1], w1_[2], w1_[3]);                         \
    } while (0)

#define MFMA_PHASE(A, XTB) do {                                                 \
        _Pragma("unroll")                                                       \
        for (int kw_ = 0; kw_ < 2; ++kw_) {                                     \
            _Pragma("unroll")                                                   \
            for (int nt_ = 0; nt_ < 4; ++nt_) {                                 \
                const bf16x8 bv_ = *reinterpret_cast<const bf16x8*>(            \
                    XTB + (size_t)(nt_ * 16 + (lane & 15)) * BKP                \
                        + kw_ * 32 + (lane >> 4) * 8);                          \
                acc[0][nt_] = __builtin_amdgcn_mfma_f32_16x16x32_bf16(          \
                    A[kw_], bv_, acc[0][nt_], 0, 0, 0);                         \
                acc[1][nt_] = __builtin_amdgcn_mfma_f32_16x16x32_bf16(          \
                    A[2 + kw_], bv_, acc[1][nt_], 0, 0, 0);                     \
            }                                                                   \
        }                                                                       \
    } while (0)

// raw barrier: drain LDS only; global loads stay in flight
#define BAR() do {                                                              \
        asm volatile("s_waitcnt lgkmcnt(0)" ::: "memory");                      \
        __builtin_amdgcn_s_barrier();                                           \
        __builtin_amdgcn_sched_barrier(0);                                      \
    } while (0)

    float2 rA0, rA1, rA2, rA3, rA4, rA5, rA6, rA7;
    float2 rB0, rB1, rB2, rB3, rB4, rB5, rB6, rB7;
    float2 rC0, rC1, rC2, rC3, rC4, rC5, rC6, rC7;
    float2 rD0, rD1, rD2, rD3, rD4, rD5, rD6, rD7;
    bf16x8 aA[4], aB[4];

    STAGE_LOAD(rA); STAGE_LOAD(rB); STAGE_LOAD(rC); STAGE_LOAD(rD);  // j=0..3
    LOAD_A(aA, 0); LOAD_A(aB, 1);

    // steady state: 7 trips x 4 iters (j = 0..27), all loads unconditional
    for (int itp = 0; itp < 7; ++itp) {
        const int j0 = 4 * itp;
        PACK_WRITE(rA, XT0); STAGE_LOAD(rA); BAR();
        MFMA_PHASE(aA, XT0); LOAD_A(aA, j0 + 2);
        PACK_WRITE(rB, XT1); STAGE_LOAD(rB); BAR();
        MFMA_PHASE(aB, XT1); LOAD_A(aB, j0 + 3);
        PACK_WRITE(rC, XT0); STAGE_LOAD(rC); BAR();
        MFMA_PHASE(aA, XT0); LOAD_A(aA, j0 + 4);
        PACK_WRITE(rD, XT1); STAGE_LOAD(rD); BAR();
        MFMA_PHASE(aB, XT1); LOAD_A(aB, j0 + 5);
    }
    // epilogue iters j=28..31 (no more staging)
    PACK_WRITE(rA, XT0); BAR(); MFMA_PHASE(aA, XT0); LOAD_A(aA, 30);
    PACK_WRITE(rB, XT1); BAR(); MFMA_PHASE(aB, XT1); LOAD_A(aB, 31);
    PACK_WRITE(rC, XT0); BAR(); MFMA_PHASE(aA, XT0);
    PACK_WRITE(rD, XT1); BAR(); MFMA_PHASE(aB, XT1);

    __syncthreads();                           // full drain; XT -> dotsL overlay
    // acc -> dots LDS ; C/D map: col=lane&15, row=4*(lane>>4)+reg (m89-verified)
#pragma unroll
    for (int rt = 0; rt < 2; ++rt)
#pragma unroll
        for (int nt = 0; nt < 4; ++nt)
#pragma unroll
            for (int rr = 0; rr < 4; ++rr)
                dotsL[(size_t)(16 * (2 * w + rt) + 4 * (lane >> 4) + rr) * 66 +
                      nt * 16 + (lane & 15)] = acc[rt][nt][rr];
    xsqp[kc * 64 + 2 * pr] = xs0;
    xsqp[kc * 64 + 2 * pr + 1] = xs1;
    if (tid < MROWS) asq_s[tid] = asq_g[tid];
    __syncthreads();

    // softmax over rows 0..112 per column; wave q handles a row chunk
    const int j = tid & 63;
    const int q = tid >> 6;
    float xsq = 0.f;
#pragma unroll
    for (int g = 0; g < 8; ++g) xsq += xsqp[g * 64 + j];
    const int rbeg = 29 * q;
    const int rend = (rbeg + 29 < KB) ? rbeg + 29 : KB;

    float m = -3.4e38f;
    for (int row = rbeg; row < rend; ++row) {
        const float d2 = asq_s[row] + xsq - 2.f * dotsL[(size_t)row * 66 + j];
        const float L = -sqrtf(fmaxf(d2, 0.f));
        dotsL[(size_t)row * 66 + j] = L;
        m = fmaxf(m, L);
    }
    pm[q * 64 + j] = m;
    __syncthreads();
    const float M = fmaxf(fmaxf(pm[j], pm[64 + j]), fmaxf(pm[128 + j], pm[192 + j]));
    float s = 0.f;
    for (int row = rbeg; row < rend; ++row) s += __expf(dotsL[(size_t)row * 66 + j] - M);
    ps[q * 64 + j] = s;
    __syncthreads();
    const float S = ps[j] + ps[64 + j] + ps[128 + j] + ps[192 + j];
    const float invS = 1.f / S;
    const float xw = dotsL[(size_t)XWROW * 66 + j];   // raw dot row 113 (0 for pad cols)

    const bool jv = (n0 + j) < N;
    float* o0 = out0 + (size_t)b * KB * N + n0 + j;
    for (int row = rbeg; row < rend; ++row) {
        const float a = __expf(dotsL[(size_t)row * 66 + j] - M) * invS;
        if (jv) o0[(size_t)row * N] = a;
        if (row < K) {
            float p = a * xw;
            for (int off = 32; off; off >>= 1) p += __shfl_down(p, off);
            if (j == 0) lpart[((size_t)b * 4 + nt4) * K + row] = p;
        }
    }
}

// ---------------------------------------------------------------------------
// pq_kernel: R[o,k] = (concepts[k]-mod).w_lfc[o,k,:] ; Qs[o,k] = mod.w_lfc[o,k,:]
// ---------------------------------------------------------------------------
__global__ __launch_bounds__(256)
void pq_kernel(const float* __restrict__ wlfc, const float* __restrict__ concepts,
               const float* __restrict__ modulation,
               float* __restrict__ Rm, float* __restrict__ Qs) {
    const int wid = (blockIdx.x * 256 + threadIdx.x) >> 6;
    const int lane = threadIdx.x & 63;
    if (wid >= NCLS * K) return;
    const int o = wid / K;
    const int k = wid % K;
    const float4* wp = reinterpret_cast<const float4*>(wlfc + (size_t)o * CKC + (size_t)k * C);
    const float4* cp = reinterpret_cast<const float4*>(concepts + (size_t)k * C);
    const float4* mp = reinterpret_cast<const float4*>(modulation);
    float s1 = 0.f, s2 = 0.f;
#pragma unroll
    for (int it = 0; it < 8; ++it) {
        const int idx = it * 64 + lane;
        const float4 w4 = wp[idx];
        const float4 c4 = cp[idx];
        const float4 m4 = mp[idx];
        s1 += w4.x * c4.x + w4.y * c4.y + w4.z * c4.z + w4.w * c4.w;
        s2 += w4.x * m4.x + w4.y * m4.y + w4.z * m4.z + w4.w * m4.w;
    }
    for (int off = 32; off; off >>= 1) {
        s1 += __shfl_down(s1, off);
        s2 += __shfl_down(s2, off);
    }
    if (lane == 0) { Rm[wid] = s1 - s2; Qs[wid] = s2; }
}

// ---------------------------------------------------------------------------
// final_kernel
// ---------------------------------------------------------------------------
__global__ __launch_bounds__(256)
void final_kernel(const float* __restrict__ lpart, const float* __restrict__ bcfc,
                  const float* __restrict__ Rm, const float* __restrict__ Qs,
                  const float* __restrict__ blfc,
                  float* __restrict__ out1, float* __restrict__ out2) {
    const int b = blockIdx.x;
    const int tid = threadIdx.x;
    __shared__ float g_s[K];
    if (tid < K) {
        const float* lp = lpart + (size_t)b * 4 * K + tid;
        const float v = lp[0] + lp[K] + lp[2 * K] + lp[3 * K] + bcfc[0];
        const float g = 1.f / (1.f + __expf(-v));
        out1[b * K + tid] = g;
        g_s[tid] = g;
    }
    __syncthreads();
    if (tid < NCLS) {
        float acc = blfc[tid];
        const float* rp = Rm + (size_t)tid * K;
        const float* qp = Qs + (size_t)tid * K;
        for (int k = 0; k < K; ++k) acc = fmaf(g_s[k], rp[k], acc) + qp[k];
        out2[b * NCLS + tid] = acc;
    }
}

extern "C" void kernel_launch(void* const* d_in, const int* in_sizes, int n_in,
                              void* d_out, int out_size, void* d_ws, size_t ws_size,
                              hipStream_t stream) {
    const float* x          = (const float*)d_in[0];
    const float* concepts   = (const float*)d_in[1];
    const float* modulation = (const float*)d_in[2];
    const float* background = (const float*)d_in[3];
    const float* wcfc       = (const float*)d_in[4];
    const float* bcfc       = (const float*)d_in[5];
    const float* wlfc       = (const float*)d_in[6];
    const float* blfc       = (const float*)d_in[7];

    float* out  = (float*)d_out;
    float* out0 = out;
    float* out1 = out + OUT1_OFF;
    float* out2 = out + OUT2_OFF;

    float* ws    = (float*)d_ws;
    float* asq   = ws;                               // 128
    float* lpart = asq + MROWS;                      // 128*4*112
    float* Rm    = lpart + (size_t)B * 4 * K;        // 22400
    float* Qs    = Rm + NCLS * K;                    // 22400
    unsigned short* Afrag = (unsigned short*)(Qs + NCLS * K);  // 512KB

    asq_kernel<<<MROWS, 256, 0, stream>>>(concepts, background, wcfc, asq);
    pack_kernel<<<dim3(8, 64), 64, 0, stream>>>(concepts, background, wcfc, Afrag);
    main_kernel<<<dim3(4, B), 256, 0, stream>>>(x, Afrag, asq, out0, lpart);
    pq_kernel<<<(NCLS * K) / 4, 256, 0, stream>>>(wlfc, concepts, modulation, Rm, Qs);
    final_kernel<<<B, 256, 0, stream>>>(lpart, bcfc, Rm, Qs, blfc, out1, out2);
}